// Round 19
// baseline (341.735 us; speedup 1.0000x reference)
//
#include <hip/hip_runtime.h>
#include <stdint.h>
#include <math.h>

#define EMB 1024
#define HEADS 16
#define NB 2
#define NS 2048
#define HD 64
#define NTOK (NB*NS)          // 4096
#define KVBLK 64
#define SEXP2 0.04508421676368185f   // log2(e)/32; sqrt folded into qhb

typedef __attribute__((ext_vector_type(8))) short short8;
typedef __attribute__((ext_vector_type(4))) float f32x4;
typedef __attribute__((ext_vector_type(4))) unsigned int u32x4;

// round-to-nearest-even f32 -> bf16 bits (epilogues / cvt only)
__device__ inline unsigned short f2bf(float f) {
  unsigned int x = __builtin_bit_cast(unsigned int, f);
  x += 0x7FFFu + ((x >> 16) & 1u);
  return (unsigned short)(x >> 16);
}

// HW packed f32x2 -> bf16x2 (RNE); no builtin on gfx950 (T12 recipe)
__device__ inline unsigned cvt_pk_bf16(float lo, float hi) {
  unsigned d;
  asm("v_cvt_pk_bf16_f32 %0, %1, %2" : "=v"(d) : "v"(lo), "v"(hi));
  return d;
}

// async global->LDS, 16B per lane; lds dest = wave-uniform base + lane*16
__device__ inline void gld16(const void* g, void* l) {
  __builtin_amdgcn_global_load_lds(
      (const __attribute__((address_space(1))) unsigned int*)g,
      (__attribute__((address_space(3))) unsigned int*)l, 16, 0, 0);
}

// x, wq, wu conversions in ONE launch (3-way range branch)
__global__ void cvt_bf16x3_kernel(const float* __restrict__ s0,
                                  unsigned short* __restrict__ d0, int n0,
                                  const float* __restrict__ s1,
                                  unsigned short* __restrict__ d1, int n1,
                                  const float* __restrict__ s2,
                                  unsigned short* __restrict__ d2, int n2) {
  int i = (blockIdx.x * blockDim.x + threadIdx.x) * 8;
  const float* s; unsigned short* d;
  if (i < n0) { s = s0 + i; d = d0 + i; }
  else if (i - n0 < n1) { s = s1 + (i - n0); d = d1 + (i - n0); }
  else if (i - n0 - n1 < n2) { s = s2 + (i - n0 - n1); d = d2 + (i - n0 - n1); }
  else return;
  float4 v0 = *reinterpret_cast<const float4*>(s);
  float4 v1 = *reinterpret_cast<const float4*>(s + 4);
  short8 o;
  o[0] = (short)f2bf(v0.x); o[1] = (short)f2bf(v0.y);
  o[2] = (short)f2bf(v0.z); o[3] = (short)f2bf(v0.w);
  o[4] = (short)f2bf(v1.x); o[5] = (short)f2bf(v1.y);
  o[6] = (short)f2bf(v1.z); o[7] = (short)f2bf(v1.w);
  *reinterpret_cast<short8*>(d) = o;
}

// per-slab transpose: src [32][2048][64] -> dst [32][64][2048], with the
// kv index PERMUTED within each 64-tile by invpi (matches in-register P
// packing of the swapped-QK^T path):
//   pv position p = kk*32 + g*8 + j  holds  kv = kk*32 + (j>>2)*16 + g*4 + (j&3)
//   invpi(p) = (p&32) | (((p>>2)&1)<<4) | (((p>>3)&3)<<2) | (p&3)
__global__ __launch_bounds__(256) void transpose_kernel(
    const unsigned short* __restrict__ src, unsigned short* __restrict__ dst) {
  __shared__ unsigned short t[64][72];   // pad: row stride 144B
  const int slab = blockIdx.y, kt = blockIdx.x;
  const unsigned short* s = src + ((size_t)slab * NS + kt * 64) * HD;
  unsigned short* d = dst + (size_t)slab * HD * NS + kt * 64;
  const int tid = threadIdx.x;
  #pragma unroll
  for (int c = 0; c < 2; ++c) {
    int idx = c * 256 + tid;             // 0..511
    int row = idx >> 3, col = (idx & 7) * 8;
    short8 v = *reinterpret_cast<const short8*>(s + row * HD + col);
    *reinterpret_cast<short8*>(&t[row][col]) = v;
  }
  __syncthreads();
  #pragma unroll
  for (int c = 0; c < 2; ++c) {
    int idx = c * 256 + tid;
    int drow = idx >> 3, col = (idx & 7) * 8;
    short8 v;
    #pragma unroll
    for (int j = 0; j < 8; ++j) {
      int p = col + j;
      int kv = (p & 32) | (((p >> 2) & 1) << 4) | (((p >> 3) & 3) << 2) | (p & 3);
      v[j] = t[kv][drow];
    }
    *reinterpret_cast<short8*>(d + (size_t)drow * NS + col) = v;
  }
}

// C[M][N] = A[M][K] * Bw[N][K]^T + bias[N].  BM=64 BN=64 BK=64 (R12/R14-
// proven: 1024 blocks = 4/CU, 16 waves/CU), dbuf, global_load_lds staging
// (linear dest + inverse-swizzled source), 2-phase. 4 waves (2x2), 32x32 out.
// OUT_BF16 path writes f2bf(v * oscale) (oscale folded at compile site).
template<bool OUT_BF16>
__global__ __launch_bounds__(256) void gemm_bt_kernel(
    const unsigned short* __restrict__ A,
    const unsigned short* __restrict__ Bw,
    const float* __restrict__ bias,
    void* __restrict__ Cout,
    float oscale,
    int M, int N, int K) {
  __shared__ __align__(16) unsigned short As[2][64 * 64];
  __shared__ __align__(16) unsigned short Bs[2][64 * 64];
  const int tid = threadIdx.x;
  const int lane = tid & 63;
  const int wave = tid >> 6;
  const int wr = wave >> 1, wc = wave & 1;
  const int g = lane >> 4, r = lane & 15;
  const int brow = blockIdx.y * 64;
  const int bcol = blockIdx.x * 64;

  const f32x4 zf = {0.f, 0.f, 0.f, 0.f};
  f32x4 acc[2][2];
  #pragma unroll
  for (int m = 0; m < 2; ++m)
    #pragma unroll
    for (int n = 0; n < 2; ++n) acc[m][n] = zf;

  auto stage = [&](int bb, int k0) {
    #pragma unroll
    for (int i = 0; i < 2; ++i) {            // A: 64x64 = 8KB = 2 issues
      int base = i * 4096 + wave * 1024;
      int L = base + lane * 16;
      int row = L >> 7, lsl = ((L >> 4) & 7) ^ (row & 7);
      gld16((const char*)A + ((size_t)(brow + row) * K + k0) * 2 + lsl * 16,
            (char*)&As[bb][0] + base);
    }
    #pragma unroll
    for (int i = 0; i < 2; ++i) {            // B: 64x64 = 8KB = 2 issues
      int base = i * 4096 + wave * 1024;
      int L = base + lane * 16;
      int row = L >> 7, lsl = ((L >> 4) & 7) ^ (row & 7);
      gld16((const char*)Bw + ((size_t)(bcol + row) * K + k0) * 2 + lsl * 16,
            (char*)&Bs[bb][0] + base);
    }
  };

  stage(0, 0);
  int cur = 0;
  for (int k0 = 0; k0 < K; k0 += 64) {
    __syncthreads();                          // drains prev stage (vmcnt)
    if (k0 + 64 < K) stage(cur ^ 1, k0 + 64);
    const char* Ac = (const char*)&As[cur][0];
    const char* Bc = (const char*)&Bs[cur][0];
    short8 af[2][2], bfr[2][2];
    #pragma unroll
    for (int m = 0; m < 2; ++m) {
      int row = wr * 32 + m * 16 + r;
      #pragma unroll
      for (int kk = 0; kk < 2; ++kk)
        af[m][kk] = *reinterpret_cast<const short8*>(
            Ac + row * 128 + ((kk * 64 + g * 16) ^ ((row & 7) << 4)));
    }
    #pragma unroll
    for (int n = 0; n < 2; ++n) {
      int row = wc * 32 + n * 16 + r;
      #pragma unroll
      for (int kk = 0; kk < 2; ++kk)
        bfr[n][kk] = *reinterpret_cast<const short8*>(
            Bc + row * 128 + ((kk * 64 + g * 16) ^ ((row & 7) << 4)));
    }
    #pragma unroll
    for (int kk = 0; kk < 2; ++kk)
      #pragma unroll
      for (int m = 0; m < 2; ++m)
        #pragma unroll
        for (int n = 0; n < 2; ++n)
          acc[m][n] = __builtin_amdgcn_mfma_f32_16x16x32_bf16(af[m][kk], bfr[n][kk], acc[m][n], 0, 0, 0);
    cur ^= 1;
  }

  #pragma unroll
  for (int n = 0; n < 2; ++n) {
    int col = bcol + wc * 32 + n * 16 + r;
    float bv = bias[col];
    #pragma unroll
    for (int m = 0; m < 2; ++m) {
      #pragma unroll
      for (int reg = 0; reg < 4; ++reg) {
        int row = brow + wr * 32 + m * 16 + g * 4 + reg;
        float v = acc[m][n][reg] + bv;
        if (OUT_BF16)
          ((unsigned short*)Cout)[(size_t)row * N + col] = f2bf(v * oscale);
        else
          ((float*)Cout)[(size_t)row * N + col] = v;
      }
    }
  }
}

// Flash attention: QW=32, EXACT kv-split x4 (no-max softmax = order-free kv
// sum). Block = 16 waves = 4 q-subtiles(32 rows) x 4 kv-streams; stream h
// owns kv tiles {4t+h}, t=0..7, SINGLE-buffered (stage -> sync -> compute ->
// sync). LDS 64KB -> 2 blocks/CU = 32 waves/CU (hardware max).
// Compute body/staging math = R18 verbatim; epilogue = staged 3-writer
// reduction through dead staging LDS, then R18's normalize/write.
__global__ __launch_bounds__(1024, 8) void attn_kernel(
    const unsigned short* __restrict__ qhb,
    const unsigned short* __restrict__ vtb,
    unsigned short* __restrict__ ob) {
  const int bid = blockIdx.x;            // 0..511
  const int xcd = bid & 7, idx = bid >> 3;   // idx 0..63
  const int slab = xcd * 4 + (idx >> 4);
  const int qtile = idx & 15;            // 128 q-rows per block
  const unsigned short* Qs = qhb + (size_t)slab * NS * HD;   // K and Q source
  const unsigned short* Vts = vtb + (size_t)slab * HD * NS;  // [64][2048] pi-perm
  unsigned short* Os = ob + (size_t)slab * NS * HD;
  const int tid = threadIdx.x;
  const int lane = tid & 63;
  const int wave = tid >> 6;             // 0..15
  const int qsub = wave >> 2;            // 0..3: which 32 q-rows
  const int h = wave & 3;                // 0..3: kv stream
  const int g = lane >> 4, r = lane & 15;
  const int qrow0 = qtile * 128 + qsub * 32;
  const int rkey = (r & 7) << 4;

  __shared__ __align__(16) char smem[65536];
  char* Kst = smem + h * 8192;           // stream h K tile (single buf)
  char* Vst = smem + 32768 + h * 8192;   // stream h V tile (single buf)

  // stream h's tile t = global kv tile 4t+h; staged by the 4 waves of
  // stream h (2 gld16 per tensor per wave). Address math = R18 verbatim.
  auto stage = [&](int t) {
    int kt4 = 4 * t + h;
    const char* Kg = (const char*)Qs + (size_t)kt4 * 8192;   // 8KB K tile
    const char* Vg = (const char*)Vts + (size_t)kt4 * 128;   // col offset
    #pragma unroll
    for (int i = 0; i < 2; ++i) {
      int base = (qsub * 2 + i) * 1024;
      int L = base + lane * 16;
      int row = L >> 7, lsl = ((L >> 4) & 7) ^ (row & 7);
      gld16(Kg + row * 128 + lsl * 16, Kst + base);
      gld16(Vg + (size_t)row * (NS * 2) + lsl * 16, Vst + base);
    }
  };

  // Q fragments (half-scaled): B operand of swapped QK^T:
  // col q = qrow0 + m*16 + r, k d = kk*32 + g*8..+7
  short8 aq[2][2];
  #pragma unroll
  for (int m = 0; m < 2; ++m)
    #pragma unroll
    for (int kk = 0; kk < 2; ++kk)
      aq[m][kk] = *reinterpret_cast<const short8*>(
          &Qs[(size_t)(qrow0 + m * 16 + r) * HD + kk * 32 + g * 8]);

  const f32x4 zf = {0.f, 0.f, 0.f, 0.f};
  f32x4 o_acc[2][4];
  float l_lane[2] = {0.f, 0.f};          // partial l for q = m*16 + r
  #pragma unroll
  for (int m = 0; m < 2; ++m)
    #pragma unroll
    for (int n = 0; n < 4; ++n) o_acc[m][n] = zf;

  for (int t = 0; t < 8; ++t) {          // 8 iters per stream
    stage(t);
    __syncthreads();                     // drain gld16, tile visible
    const char* Kc = Kst;
    const char* Vc = Vst;

    // S^T = K Q^T : lane(g,r) gets S[kv=jb*16+g*4+reg][q=m*16+r]
    f32x4 s[2][4];
    __builtin_amdgcn_s_setprio(1);
    #pragma unroll
    for (int jb = 0; jb < 4; ++jb) {
      short8 bk[2];
      #pragma unroll
      for (int kk = 0; kk < 2; ++kk)
        bk[kk] = *reinterpret_cast<const short8*>(
            Kc + (jb * 16 + r) * 128 + ((kk * 64 + g * 16) ^ rkey));
      #pragma unroll
      for (int m = 0; m < 2; ++m) {
        s[m][jb] = zf;
        #pragma unroll
        for (int kk = 0; kk < 2; ++kk)
          s[m][jb] = __builtin_amdgcn_mfma_f32_16x16x32_bf16(bk[kk], aq[m][kk], s[m][jb], 0, 0, 0);
      }
    }
    __builtin_amdgcn_s_setprio(0);

    // p = 2^(s); row-sum into per-lane l; pack PV A-frags in-register:
    // ap[m][kk][j] = P[q=m*16+r][kv = kk*32 + (j>>2)*16 + g*4 + (j&3)]
    short8 ap[2][2];
    #pragma unroll
    for (int m = 0; m < 2; ++m) {
      float p[4][4];
      #pragma unroll
      for (int jb = 0; jb < 4; ++jb)
        #pragma unroll
        for (int reg = 0; reg < 4; ++reg)
          p[jb][reg] = __builtin_amdgcn_exp2f(s[m][jb][reg]);
      float t0 = (p[0][0] + p[0][1]) + (p[0][2] + p[0][3]);
      float t1 = (p[1][0] + p[1][1]) + (p[1][2] + p[1][3]);
      float t2 = (p[2][0] + p[2][1]) + (p[2][2] + p[2][3]);
      float t3 = (p[3][0] + p[3][1]) + (p[3][2] + p[3][3]);
      l_lane[m] += (t0 + t1) + (t2 + t3);
      #pragma unroll
      for (int kk = 0; kk < 2; ++kk) {
        u32x4 w;
        w.x = cvt_pk_bf16(p[2 * kk][0], p[2 * kk][1]);
        w.y = cvt_pk_bf16(p[2 * kk][2], p[2 * kk][3]);
        w.z = cvt_pk_bf16(p[2 * kk + 1][0], p[2 * kk + 1][1]);
        w.w = cvt_pk_bf16(p[2 * kk + 1][2], p[2 * kk + 1][3]);
        ap[m][kk] = __builtin_bit_cast(short8, w);
      }
    }

    // O += P V (pi order): B[k_pv][col=d] from Vt rows n*16+r
    __builtin_amdgcn_s_setprio(1);
    #pragma unroll
    for (int n = 0; n < 4; ++n) {
      short8 bv[2];
      #pragma unroll
      for (int kk = 0; kk < 2; ++kk)
        bv[kk] = *reinterpret_cast<const short8*>(
            Vc + (n * 16 + r) * 128 + ((kk * 64 + g * 16) ^ rkey));
      #pragma unroll
      for (int m = 0; m < 2; ++m)
        #pragma unroll
        for (int kk = 0; kk < 2; ++kk)
          o_acc[m][n] = __builtin_amdgcn_mfma_f32_16x16x32_bf16(ap[m][kk], bv[kk], o_acc[m][n], 0, 0, 0);
    }
    __builtin_amdgcn_s_setprio(0);
    __syncthreads();                     // all reads done; safe to overwrite
  }

  // cross-stream reduction through the (now dead) 64KB staging LDS.
  // redL: 12 slots x 512B (l partials). redO: 12 slots x 4KB (one m at a
  // time; lanes contiguous 16B -> conflict-free).
  char* redL = smem;                     // 6KB
  char* redO = smem + 8192;              // 48KB
  if (h != 0) {
    int slot = (h - 1) * 4 + qsub;
    float2 lp; lp.x = l_lane[0]; lp.y = l_lane[1];
    *reinterpret_cast<float2*>(redL + slot * 512 + lane * 8) = lp;
    #pragma unroll
    for (int n = 0; n < 4; ++n)
      *reinterpret_cast<f32x4*>(redO + slot * 4096 + n * 1024 + lane * 16) = o_acc[0][n];
  }
  __syncthreads();
  if (h == 0) {
    #pragma unroll
    for (int w = 0; w < 3; ++w) {
      int slot = w * 4 + qsub;
      float2 lp = *reinterpret_cast<float2*>(redL + slot * 512 + lane * 8);
      l_lane[0] += lp.x; l_lane[1] += lp.y;
      #pragma unroll
      for (int n = 0; n < 4; ++n)
        o_acc[0][n] += *reinterpret_cast<f32x4*>(
            redO + slot * 4096 + n * 1024 + lane * 16);
    }
  }
  __syncthreads();                       // m=0 slab consumed
  if (h != 0) {
    int slot = (h - 1) * 4 + qsub;
    #pragma unroll
    for (int n = 0; n < 4; ++n)
      *reinterpret_cast<f32x4*>(redO + slot * 4096 + n * 1024 + lane * 16) = o_acc[1][n];
  }
  __syncthreads();
  if (h == 0) {
    #pragma unroll
    for (int w = 0; w < 3; ++w) {
      int slot = w * 4 + qsub;
      #pragma unroll
      for (int n = 0; n < 4; ++n)
        o_acc[1][n] += *reinterpret_cast<f32x4*>(
            redO + slot * 4096 + n * 1024 + lane * 16);
    }

    // epilogue: complete l across g-lanes, normalize, un-scale V's sqrt(c)
    const float rsqc = 1.0f / sqrtf(SEXP2);   // compile-time folded
    #pragma unroll
    for (int m = 0; m < 2; ++m) {
      float l = l_lane[m];
      l += __shfl_xor(l, 16);
      l += __shfl_xor(l, 32);                 // all lanes: full l[q=m*16+r]
      #pragma unroll
      for (int reg = 0; reg < 4; ++reg) {
        float inv = rsqc / __shfl(l, g * 4 + reg);
        int row = qrow0 + m * 16 + g * 4 + reg;
        #pragma unroll
        for (int n = 0; n < 4; ++n)
          Os[(size_t)row * HD + n * 16 + r] = f2bf(o_acc[m][n][reg] * inv);
      }
    }
  }
}

extern "C" void kernel_launch(void* const* d_in, const int* in_sizes, int n_in,
                              void* d_out, int out_size, void* d_ws, size_t ws_size,
                              hipStream_t stream) {
  const float* x  = (const float*)d_in[0];
  const float* wq = (const float*)d_in[1];
  const float* bq = (const float*)d_in[2];
  const float* wu = (const float*)d_in[3];
  const float* bu = (const float*)d_in[4];
  float* out = (float*)d_out;

  char* ws = (char*)d_ws;
  unsigned short* xb  = (unsigned short*)(ws);                 // 8 MB (reused as vtb)
  unsigned short* qhb = (unsigned short*)(ws + (8u  << 20));   // 8 MB: bf16(q*sqrt(c))
  unsigned short* ob  = (unsigned short*)(ws + (16u << 20));   // 8 MB: attn output
  unsigned short* wqb = (unsigned short*)(ws + (24u << 20));   // 2 MB
  unsigned short* wub = (unsigned short*)(ws + (26u << 20));   // 2 MB

  // all three f32->bf16 conversions in one launch
  const int nx = NTOK * EMB, nw = EMB * EMB;
  cvt_bf16x3_kernel<<<((nx + 2 * nw) / 8 + 255) / 256, 256, 0, stream>>>(
      x, xb, nx, wq, wqb, nw, wu, wub, nw);

  // q = x @ wq^T + bq -> qhb = bf16(q * sqrt(c)), single rounded
  gemm_bt_kernel<true><<<dim3(EMB / 64, NTOK / 64), 256, 0, stream>>>(
      xb, wqb, bq, qhb, sqrtf(SEXP2), NTOK, EMB, EMB);

  // xb is dead now; reuse as vtb: per-slab pi-permuted transpose of qhb
  unsigned short* vtb = xb;
  transpose_kernel<<<dim3(NS / 64, HEADS * NB), 256, 0, stream>>>(qhb, vtb);

  // 512 blocks (16 qtiles x 32 slabs) x 1024 threads; XCD swizzle in-kernel
  attn_kernel<<<dim3(512), 1024, 0, stream>>>(qhb, vtb, ob);

  // y = O @ wu^T + bu -> f32
  gemm_bt_kernel<false><<<dim3(EMB / 64, NTOK / 64), 256, 0, stream>>>(
      ob, wub, bu, out, 1.0f, NTOK, EMB, EMB);
}

// Round 20
// 102.246 us; speedup vs baseline: 3.3423x; 3.3423x over previous
//
#include <hip/hip_runtime.h>
#include <stdint.h>
#include <math.h>

#define EMB 1024
#define HEADS 16
#define NB 2
#define NS 2048
#define HD 64
#define NTOK (NB*NS)          // 4096
#define KVBLK 64
#define SEXP2 0.04508421676368185f   // log2(e)/32; sqrt folded into qhb

typedef __attribute__((ext_vector_type(8))) short short8;
typedef __attribute__((ext_vector_type(4))) float f32x4;
typedef __attribute__((ext_vector_type(4))) unsigned int u32x4;

// round-to-nearest-even f32 -> bf16 bits (epilogues / cvt only)
__device__ inline unsigned short f2bf(float f) {
  unsigned int x = __builtin_bit_cast(unsigned int, f);
  x += 0x7FFFu + ((x >> 16) & 1u);
  return (unsigned short)(x >> 16);
}

// HW packed f32x2 -> bf16x2 (RNE); no builtin on gfx950 (T12 recipe)
__device__ inline unsigned cvt_pk_bf16(float lo, float hi) {
  unsigned d;
  asm("v_cvt_pk_bf16_f32 %0, %1, %2" : "=v"(d) : "v"(lo), "v"(hi));
  return d;
}

// async global->LDS, 16B per lane; lds dest = wave-uniform base + lane*16
__device__ inline void gld16(const void* g, void* l) {
  __builtin_amdgcn_global_load_lds(
      (const __attribute__((address_space(1))) unsigned int*)g,
      (__attribute__((address_space(3))) unsigned int*)l, 16, 0, 0);
}

// x, wq, wu conversions in ONE launch (3-way range branch)
__global__ void cvt_bf16x3_kernel(const float* __restrict__ s0,
                                  unsigned short* __restrict__ d0, int n0,
                                  const float* __restrict__ s1,
                                  unsigned short* __restrict__ d1, int n1,
                                  const float* __restrict__ s2,
                                  unsigned short* __restrict__ d2, int n2) {
  int i = (blockIdx.x * blockDim.x + threadIdx.x) * 8;
  const float* s; unsigned short* d;
  if (i < n0) { s = s0 + i; d = d0 + i; }
  else if (i - n0 < n1) { s = s1 + (i - n0); d = d1 + (i - n0); }
  else if (i - n0 - n1 < n2) { s = s2 + (i - n0 - n1); d = d2 + (i - n0 - n1); }
  else return;
  float4 v0 = *reinterpret_cast<const float4*>(s);
  float4 v1 = *reinterpret_cast<const float4*>(s + 4);
  short8 o;
  o[0] = (short)f2bf(v0.x); o[1] = (short)f2bf(v0.y);
  o[2] = (short)f2bf(v0.z); o[3] = (short)f2bf(v0.w);
  o[4] = (short)f2bf(v1.x); o[5] = (short)f2bf(v1.y);
  o[6] = (short)f2bf(v1.z); o[7] = (short)f2bf(v1.w);
  *reinterpret_cast<short8*>(d) = o;
}

// per-slab transpose: src [32][2048][64] -> dst [32][64][2048], with the
// kv index PERMUTED within each 64-tile by invpi (matches in-register P
// packing of the swapped-QK^T path):
//   pv position p = kk*32 + g*8 + j  holds  kv = kk*32 + (j>>2)*16 + g*4 + (j&3)
//   invpi(p) = (p&32) | (((p>>2)&1)<<4) | (((p>>3)&3)<<2) | (p&3)
__global__ __launch_bounds__(256) void transpose_kernel(
    const unsigned short* __restrict__ src, unsigned short* __restrict__ dst) {
  __shared__ unsigned short t[64][72];   // pad: row stride 144B
  const int slab = blockIdx.y, kt = blockIdx.x;
  const unsigned short* s = src + ((size_t)slab * NS + kt * 64) * HD;
  unsigned short* d = dst + (size_t)slab * HD * NS + kt * 64;
  const int tid = threadIdx.x;
  #pragma unroll
  for (int c = 0; c < 2; ++c) {
    int idx = c * 256 + tid;             // 0..511
    int row = idx >> 3, col = (idx & 7) * 8;
    short8 v = *reinterpret_cast<const short8*>(s + row * HD + col);
    *reinterpret_cast<short8*>(&t[row][col]) = v;
  }
  __syncthreads();
  #pragma unroll
  for (int c = 0; c < 2; ++c) {
    int idx = c * 256 + tid;
    int drow = idx >> 3, col = (idx & 7) * 8;
    short8 v;
    #pragma unroll
    for (int j = 0; j < 8; ++j) {
      int p = col + j;
      int kv = (p & 32) | (((p >> 2) & 1) << 4) | (((p >> 3) & 3) << 2) | (p & 3);
      v[j] = t[kv][drow];
    }
    *reinterpret_cast<short8*>(d + (size_t)drow * NS + col) = v;
  }
}

// C[M][N] = A[M][K] * Bw[N][K]^T + bias[N].  BM=64 BN=64 BK=64 (R12/R14-
// proven: 1024 blocks = 4/CU, 16 waves/CU), dbuf, global_load_lds staging
// (linear dest + inverse-swizzled source), 2-phase. 4 waves (2x2), 32x32 out.
// OUT_BF16 path writes f2bf(v * oscale) (oscale folded at compile site).
template<bool OUT_BF16>
__global__ __launch_bounds__(256) void gemm_bt_kernel(
    const unsigned short* __restrict__ A,
    const unsigned short* __restrict__ Bw,
    const float* __restrict__ bias,
    void* __restrict__ Cout,
    float oscale,
    int M, int N, int K) {
  __shared__ __align__(16) unsigned short As[2][64 * 64];
  __shared__ __align__(16) unsigned short Bs[2][64 * 64];
  const int tid = threadIdx.x;
  const int lane = tid & 63;
  const int wave = tid >> 6;
  const int wr = wave >> 1, wc = wave & 1;
  const int g = lane >> 4, r = lane & 15;
  const int brow = blockIdx.y * 64;
  const int bcol = blockIdx.x * 64;

  const f32x4 zf = {0.f, 0.f, 0.f, 0.f};
  f32x4 acc[2][2];
  #pragma unroll
  for (int m = 0; m < 2; ++m)
    #pragma unroll
    for (int n = 0; n < 2; ++n) acc[m][n] = zf;

  auto stage = [&](int bb, int k0) {
    #pragma unroll
    for (int i = 0; i < 2; ++i) {            // A: 64x64 = 8KB = 2 issues
      int base = i * 4096 + wave * 1024;
      int L = base + lane * 16;
      int row = L >> 7, lsl = ((L >> 4) & 7) ^ (row & 7);
      gld16((const char*)A + ((size_t)(brow + row) * K + k0) * 2 + lsl * 16,
            (char*)&As[bb][0] + base);
    }
    #pragma unroll
    for (int i = 0; i < 2; ++i) {            // B: 64x64 = 8KB = 2 issues
      int base = i * 4096 + wave * 1024;
      int L = base + lane * 16;
      int row = L >> 7, lsl = ((L >> 4) & 7) ^ (row & 7);
      gld16((const char*)Bw + ((size_t)(bcol + row) * K + k0) * 2 + lsl * 16,
            (char*)&Bs[bb][0] + base);
    }
  };

  stage(0, 0);
  int cur = 0;
  for (int k0 = 0; k0 < K; k0 += 64) {
    __syncthreads();                          // drains prev stage (vmcnt)
    if (k0 + 64 < K) stage(cur ^ 1, k0 + 64);
    const char* Ac = (const char*)&As[cur][0];
    const char* Bc = (const char*)&Bs[cur][0];
    short8 af[2][2], bfr[2][2];
    #pragma unroll
    for (int m = 0; m < 2; ++m) {
      int row = wr * 32 + m * 16 + r;
      #pragma unroll
      for (int kk = 0; kk < 2; ++kk)
        af[m][kk] = *reinterpret_cast<const short8*>(
            Ac + row * 128 + ((kk * 64 + g * 16) ^ ((row & 7) << 4)));
    }
    #pragma unroll
    for (int n = 0; n < 2; ++n) {
      int row = wc * 32 + n * 16 + r;
      #pragma unroll
      for (int kk = 0; kk < 2; ++kk)
        bfr[n][kk] = *reinterpret_cast<const short8*>(
            Bc + row * 128 + ((kk * 64 + g * 16) ^ ((row & 7) << 4)));
    }
    #pragma unroll
    for (int kk = 0; kk < 2; ++kk)
      #pragma unroll
      for (int m = 0; m < 2; ++m)
        #pragma unroll
        for (int n = 0; n < 2; ++n)
          acc[m][n] = __builtin_amdgcn_mfma_f32_16x16x32_bf16(af[m][kk], bfr[n][kk], acc[m][n], 0, 0, 0);
    cur ^= 1;
  }

  #pragma unroll
  for (int n = 0; n < 2; ++n) {
    int col = bcol + wc * 32 + n * 16 + r;
    float bv = bias[col];
    #pragma unroll
    for (int m = 0; m < 2; ++m) {
      #pragma unroll
      for (int reg = 0; reg < 4; ++reg) {
        int row = brow + wr * 32 + m * 16 + g * 4 + reg;
        float v = acc[m][n][reg] + bv;
        if (OUT_BF16)
          ((unsigned short*)Cout)[(size_t)row * N + col] = f2bf(v * oscale);
        else
          ((float*)Cout)[(size_t)row * N + col] = v;
      }
    }
  }
}

// Flash attention: R18 geometry/body (8 waves = 4 q-subtiles x 2 kv-streams,
// QW=32, setprio, half-scale Q) but SINGLE-buffered streams: LDS 32KB ->
// 4 blocks/CU = 32 waves/CU (hardware max; R19's occupancy goal without the
// VGPR-spill). Schedule: stage(t) -> sync (drains vmcnt) -> compute -> sync.
// Epilogue: 2-phase (m=0+l, then m=1) reduction through dead staging LDS.
__global__ __launch_bounds__(512) void attn_kernel(
    const unsigned short* __restrict__ qhb,
    const unsigned short* __restrict__ vtb,
    unsigned short* __restrict__ ob) {
  const int bid = blockIdx.x;            // 0..511
  const int xcd = bid & 7, idx = bid >> 3;   // idx 0..63
  const int slab = xcd * 4 + (idx >> 4);
  const int qtile = idx & 15;            // 128 q-rows per block
  const unsigned short* Qs = qhb + (size_t)slab * NS * HD;   // K and Q source
  const unsigned short* Vts = vtb + (size_t)slab * HD * NS;  // [64][2048] pi-perm
  unsigned short* Os = ob + (size_t)slab * NS * HD;
  const int tid = threadIdx.x;
  const int lane = tid & 63;
  const int wave = tid >> 6;             // 0..7
  const int qsub = wave >> 1;            // 0..3: which 32 q-rows
  const int h = wave & 1;                // 0/1: kv stream
  const int g = lane >> 4, r = lane & 15;
  const int qrow0 = qtile * 128 + qsub * 32;
  const int rkey = (r & 7) << 4;

  __shared__ __align__(16) unsigned short K_lds[2][KVBLK * HD];   // [h], 16KB
  __shared__ __align__(16) unsigned short Vt_lds[2][HD * KVBLK];  // [h], 16KB

  // stream h's tile t = global kv tile 2t+h; staged by the 4 waves of
  // stream h (2 gld16 per tensor per wave). Address math = R18 verbatim.
  auto stage = [&](int t) {
    int kt2 = 2 * t + h;
    const char* Kg = (const char*)Qs + (size_t)kt2 * 8192;   // 8KB K tile
    const char* Vg = (const char*)Vts + (size_t)kt2 * 128;   // col offset
    #pragma unroll
    for (int i = 0; i < 2; ++i) {
      int base = (qsub * 2 + i) * 1024;
      int L = base + lane * 16;
      int row = L >> 7, lsl = ((L >> 4) & 7) ^ (row & 7);
      gld16(Kg + row * 128 + lsl * 16, (char*)&K_lds[h][0] + base);
      gld16(Vg + (size_t)row * (NS * 2) + lsl * 16, (char*)&Vt_lds[h][0] + base);
    }
  };

  // Q fragments (half-scaled): B operand of swapped QK^T:
  // col q = qrow0 + m*16 + r, k d = kk*32 + g*8..+7
  short8 aq[2][2];
  #pragma unroll
  for (int m = 0; m < 2; ++m)
    #pragma unroll
    for (int kk = 0; kk < 2; ++kk)
      aq[m][kk] = *reinterpret_cast<const short8*>(
          &Qs[(size_t)(qrow0 + m * 16 + r) * HD + kk * 32 + g * 8]);

  const f32x4 zf = {0.f, 0.f, 0.f, 0.f};
  f32x4 o_acc[2][4];
  float l_lane[2] = {0.f, 0.f};          // partial l for q = m*16 + r
  #pragma unroll
  for (int m = 0; m < 2; ++m)
    #pragma unroll
    for (int n = 0; n < 4; ++n) o_acc[m][n] = zf;

  for (int t = 0; t < 16; ++t) {         // 16 iters per stream
    stage(t);
    __syncthreads();                     // drains gld16 (vmcnt) + visibility
    const char* Kc = (const char*)&K_lds[h][0];
    const char* Vc = (const char*)&Vt_lds[h][0];

    // S^T = K Q^T : lane(g,r) gets S[kv=jb*16+g*4+reg][q=m*16+r]
    f32x4 s[2][4];
    __builtin_amdgcn_s_setprio(1);
    #pragma unroll
    for (int jb = 0; jb < 4; ++jb) {
      short8 bk[2];
      #pragma unroll
      for (int kk = 0; kk < 2; ++kk)
        bk[kk] = *reinterpret_cast<const short8*>(
            Kc + (jb * 16 + r) * 128 + ((kk * 64 + g * 16) ^ rkey));
      #pragma unroll
      for (int m = 0; m < 2; ++m) {
        s[m][jb] = zf;
        #pragma unroll
        for (int kk = 0; kk < 2; ++kk)
          s[m][jb] = __builtin_amdgcn_mfma_f32_16x16x32_bf16(bk[kk], aq[m][kk], s[m][jb], 0, 0, 0);
      }
    }
    __builtin_amdgcn_s_setprio(0);

    // p = 2^(s); row-sum into per-lane l; pack PV A-frags in-register:
    // ap[m][kk][j] = P[q=m*16+r][kv = kk*32 + (j>>2)*16 + g*4 + (j&3)]
    short8 ap[2][2];
    #pragma unroll
    for (int m = 0; m < 2; ++m) {
      float p[4][4];
      #pragma unroll
      for (int jb = 0; jb < 4; ++jb)
        #pragma unroll
        for (int reg = 0; reg < 4; ++reg)
          p[jb][reg] = __builtin_amdgcn_exp2f(s[m][jb][reg]);
      float t0 = (p[0][0] + p[0][1]) + (p[0][2] + p[0][3]);
      float t1 = (p[1][0] + p[1][1]) + (p[1][2] + p[1][3]);
      float t2 = (p[2][0] + p[2][1]) + (p[2][2] + p[2][3]);
      float t3 = (p[3][0] + p[3][1]) + (p[3][2] + p[3][3]);
      l_lane[m] += (t0 + t1) + (t2 + t3);
      #pragma unroll
      for (int kk = 0; kk < 2; ++kk) {
        u32x4 w;
        w.x = cvt_pk_bf16(p[2 * kk][0], p[2 * kk][1]);
        w.y = cvt_pk_bf16(p[2 * kk][2], p[2 * kk][3]);
        w.z = cvt_pk_bf16(p[2 * kk + 1][0], p[2 * kk + 1][1]);
        w.w = cvt_pk_bf16(p[2 * kk + 1][2], p[2 * kk + 1][3]);
        ap[m][kk] = __builtin_bit_cast(short8, w);
      }
    }

    // O += P V (pi order): B[k_pv][col=d] from Vt rows n*16+r
    __builtin_amdgcn_s_setprio(1);
    #pragma unroll
    for (int n = 0; n < 4; ++n) {
      short8 bv[2];
      #pragma unroll
      for (int kk = 0; kk < 2; ++kk)
        bv[kk] = *reinterpret_cast<const short8*>(
            Vc + (n * 16 + r) * 128 + ((kk * 64 + g * 16) ^ rkey));
      #pragma unroll
      for (int m = 0; m < 2; ++m)
        #pragma unroll
        for (int kk = 0; kk < 2; ++kk)
          o_acc[m][n] = __builtin_amdgcn_mfma_f32_16x16x32_bf16(ap[m][kk], bv[kk], o_acc[m][n], 0, 0, 0);
    }
    __builtin_amdgcn_s_setprio(0);
    __syncthreads();                     // reads done; safe to overwrite
  }

  // cross-stream reduction through the dead 32KB staging LDS, 2 phases:
  // phase A: l partials (2KB at Vt base) + m=0 O partials (16KB at K base);
  // phase B: m=1 O partials (same 16KB). Lanes contiguous 16B -> no conflict.
  char* redO = (char*)&K_lds[0][0];
  char* redL = (char*)&Vt_lds[0][0];
  if (h == 1) {
    float2 lp; lp.x = l_lane[0]; lp.y = l_lane[1];
    *reinterpret_cast<float2*>(redL + qsub * 512 + lane * 8) = lp;
    #pragma unroll
    for (int n = 0; n < 4; ++n)
      *reinterpret_cast<f32x4*>(redO + qsub * 4096 + n * 1024 + lane * 16) = o_acc[0][n];
  }
  __syncthreads();
  if (h == 0) {
    float2 lp = *reinterpret_cast<float2*>(redL + qsub * 512 + lane * 8);
    l_lane[0] += lp.x; l_lane[1] += lp.y;
    #pragma unroll
    for (int n = 0; n < 4; ++n)
      o_acc[0][n] += *reinterpret_cast<f32x4*>(
          redO + qsub * 4096 + n * 1024 + lane * 16);
  }
  __syncthreads();                       // phase A consumed
  if (h == 1) {
    #pragma unroll
    for (int n = 0; n < 4; ++n)
      *reinterpret_cast<f32x4*>(redO + qsub * 4096 + n * 1024 + lane * 16) = o_acc[1][n];
  }
  __syncthreads();
  if (h == 0) {
    #pragma unroll
    for (int n = 0; n < 4; ++n)
      o_acc[1][n] += *reinterpret_cast<f32x4*>(
          redO + qsub * 4096 + n * 1024 + lane * 16);

    // epilogue: complete l across g-lanes, normalize, un-scale V's sqrt(c)
    const float rsqc = 1.0f / sqrtf(SEXP2);   // compile-time folded
    #pragma unroll
    for (int m = 0; m < 2; ++m) {
      float l = l_lane[m];
      l += __shfl_xor(l, 16);
      l += __shfl_xor(l, 32);                 // all lanes: full l[q=m*16+r]
      #pragma unroll
      for (int reg = 0; reg < 4; ++reg) {
        float inv = rsqc / __shfl(l, g * 4 + reg);
        int row = qrow0 + m * 16 + g * 4 + reg;
        #pragma unroll
        for (int n = 0; n < 4; ++n)
          Os[(size_t)row * HD + n * 16 + r] = f2bf(o_acc[m][n][reg] * inv);
      }
    }
  }
}

extern "C" void kernel_launch(void* const* d_in, const int* in_sizes, int n_in,
                              void* d_out, int out_size, void* d_ws, size_t ws_size,
                              hipStream_t stream) {
  const float* x  = (const float*)d_in[0];
  const float* wq = (const float*)d_in[1];
  const float* bq = (const float*)d_in[2];
  const float* wu = (const float*)d_in[3];
  const float* bu = (const float*)d_in[4];
  float* out = (float*)d_out;

  char* ws = (char*)d_ws;
  unsigned short* xb  = (unsigned short*)(ws);                 // 8 MB (reused as vtb)
  unsigned short* qhb = (unsigned short*)(ws + (8u  << 20));   // 8 MB: bf16(q*sqrt(c))
  unsigned short* ob  = (unsigned short*)(ws + (16u << 20));   // 8 MB: attn output
  unsigned short* wqb = (unsigned short*)(ws + (24u << 20));   // 2 MB
  unsigned short* wub = (unsigned short*)(ws + (26u << 20));   // 2 MB

  // all three f32->bf16 conversions in one launch
  const int nx = NTOK * EMB, nw = EMB * EMB;
  cvt_bf16x3_kernel<<<((nx + 2 * nw) / 8 + 255) / 256, 256, 0, stream>>>(
      x, xb, nx, wq, wqb, nw, wu, wub, nw);

  // q = x @ wq^T + bq -> qhb = bf16(q * sqrt(c)), single rounded
  gemm_bt_kernel<true><<<dim3(EMB / 64, NTOK / 64), 256, 0, stream>>>(
      xb, wqb, bq, qhb, sqrtf(SEXP2), NTOK, EMB, EMB);

  // xb is dead now; reuse as vtb: per-slab pi-permuted transpose of qhb
  unsigned short* vtb = xb;
  transpose_kernel<<<dim3(NS / 64, HEADS * NB), 256, 0, stream>>>(qhb, vtb);

  // 512 blocks (16 qtiles x 32 slabs) x 512 threads; XCD swizzle in-kernel
  attn_kernel<<<dim3(512), 512, 0, stream>>>(qhb, vtb, ob);

  // y = O @ wu^T + bu -> f32
  gemm_bt_kernel<false><<<dim3(EMB / 64, NTOK / 64), 256, 0, stream>>>(
      ob, wub, bu, out, 1.0f, NTOK, EMB, EMB);
}

// Round 21
// 88.689 us; speedup vs baseline: 3.8532x; 1.1529x over previous
//
#include <hip/hip_runtime.h>
#include <stdint.h>
#include <math.h>

#define EMB 1024
#define HEADS 16
#define NB 2
#define NS 2048
#define HD 64
#define NTOK (NB*NS)          // 4096
#define KVBLK 64
#define SEXP2 0.04508421676368185f   // log2(e)/32; sqrt folded into qhb

typedef __attribute__((ext_vector_type(8))) short short8;
typedef __attribute__((ext_vector_type(4))) float f32x4;
typedef __attribute__((ext_vector_type(4))) unsigned int u32x4;

// round-to-nearest-even f32 -> bf16 bits (epilogues / cvt only)
__device__ inline unsigned short f2bf(float f) {
  unsigned int x = __builtin_bit_cast(unsigned int, f);
  x += 0x7FFFu + ((x >> 16) & 1u);
  return (unsigned short)(x >> 16);
}

// HW packed f32x2 -> bf16x2 (RNE); no builtin on gfx950 (T12 recipe)
__device__ inline unsigned cvt_pk_bf16(float lo, float hi) {
  unsigned d;
  asm("v_cvt_pk_bf16_f32 %0, %1, %2" : "=v"(d) : "v"(lo), "v"(hi));
  return d;
}

// async global->LDS, 16B per lane; lds dest = wave-uniform base + lane*16
__device__ inline void gld16(const void* g, void* l) {
  __builtin_amdgcn_global_load_lds(
      (const __attribute__((address_space(1))) unsigned int*)g,
      (__attribute__((address_space(3))) unsigned int*)l, 16, 0, 0);
}

// x, wq, wu conversions in ONE launch (3-way range branch)
__global__ void cvt_bf16x3_kernel(const float* __restrict__ s0,
                                  unsigned short* __restrict__ d0, int n0,
                                  const float* __restrict__ s1,
                                  unsigned short* __restrict__ d1, int n1,
                                  const float* __restrict__ s2,
                                  unsigned short* __restrict__ d2, int n2) {
  int i = (blockIdx.x * blockDim.x + threadIdx.x) * 8;
  const float* s; unsigned short* d;
  if (i < n0) { s = s0 + i; d = d0 + i; }
  else if (i - n0 < n1) { s = s1 + (i - n0); d = d1 + (i - n0); }
  else if (i - n0 - n1 < n2) { s = s2 + (i - n0 - n1); d = d2 + (i - n0 - n1); }
  else return;
  float4 v0 = *reinterpret_cast<const float4*>(s);
  float4 v1 = *reinterpret_cast<const float4*>(s + 4);
  short8 o;
  o[0] = (short)f2bf(v0.x); o[1] = (short)f2bf(v0.y);
  o[2] = (short)f2bf(v0.z); o[3] = (short)f2bf(v0.w);
  o[4] = (short)f2bf(v1.x); o[5] = (short)f2bf(v1.y);
  o[6] = (short)f2bf(v1.z); o[7] = (short)f2bf(v1.w);
  *reinterpret_cast<short8*>(d) = o;
}

// per-slab transpose: src [32][2048][64] -> dst [32][64][2048], with the
// kv index PERMUTED within each 64-tile by invpi (matches in-register P
// packing of the swapped-QK^T path):
//   pv position p = kk*32 + g*8 + j  holds  kv = kk*32 + (j>>2)*16 + g*4 + (j&3)
//   invpi(p) = (p&32) | (((p>>2)&1)<<4) | (((p>>3)&3)<<2) | (p&3)
__global__ __launch_bounds__(256) void transpose_kernel(
    const unsigned short* __restrict__ src, unsigned short* __restrict__ dst) {
  __shared__ unsigned short t[64][72];   // pad: row stride 144B
  const int slab = blockIdx.y, kt = blockIdx.x;
  const unsigned short* s = src + ((size_t)slab * NS + kt * 64) * HD;
  unsigned short* d = dst + (size_t)slab * HD * NS + kt * 64;
  const int tid = threadIdx.x;
  #pragma unroll
  for (int c = 0; c < 2; ++c) {
    int idx = c * 256 + tid;             // 0..511
    int row = idx >> 3, col = (idx & 7) * 8;
    short8 v = *reinterpret_cast<const short8*>(s + row * HD + col);
    *reinterpret_cast<short8*>(&t[row][col]) = v;
  }
  __syncthreads();
  #pragma unroll
  for (int c = 0; c < 2; ++c) {
    int idx = c * 256 + tid;
    int drow = idx >> 3, col = (idx & 7) * 8;
    short8 v;
    #pragma unroll
    for (int j = 0; j < 8; ++j) {
      int p = col + j;
      int kv = (p & 32) | (((p >> 2) & 1) << 4) | (((p >> 3) & 3) << 2) | (p & 3);
      v[j] = t[kv][drow];
    }
    *reinterpret_cast<short8*>(d + (size_t)drow * NS + col) = v;
  }
}

// C[M][N] = A[M][K] * Bw[N][K]^T + bias[N].  BM=64 BN=64 BK=64, 1-D grid of
// 1024 blocks with XCD-chunked swizzle: XCD k (= bid&7 under round-robin
// dispatch) owns an 8-row-panel chunk -> per-XCD L2 working set = 8 A-panels
// (1MB) + all B (2MB) = 3MB < 4MB. dbuf, global_load_lds staging (linear
// dest + inverse-swizzled source), 2-phase. 4 waves (2x2), 32x32 out.
// OUT_BF16 path writes f2bf(v * oscale) (oscale folded at compile site).
template<bool OUT_BF16>
__global__ __launch_bounds__(256) void gemm_bt_kernel(
    const unsigned short* __restrict__ A,
    const unsigned short* __restrict__ Bw,
    const float* __restrict__ bias,
    void* __restrict__ Cout,
    float oscale,
    int M, int N, int K) {
  __shared__ __align__(16) unsigned short As[2][64 * 64];
  __shared__ __align__(16) unsigned short Bs[2][64 * 64];
  const int tid = threadIdx.x;
  const int lane = tid & 63;
  const int wave = tid >> 6;
  const int wr = wave >> 1, wc = wave & 1;
  const int g = lane >> 4, r = lane & 15;
  // XCD-chunked swizzle (bijective: gridDim = (M/64)*(N/64), divisible by 8)
  const int tn = N / 64;                 // col tiles
  const int per = (M / 64) / 8;          // row tiles per XCD
  const int k8 = blockIdx.x & 7, j = blockIdx.x >> 3;
  const int brow = (k8 * per + j / tn) * 64;
  const int bcol = (j % tn) * 64;

  const f32x4 zf = {0.f, 0.f, 0.f, 0.f};
  f32x4 acc[2][2];
  #pragma unroll
  for (int m = 0; m < 2; ++m)
    #pragma unroll
    for (int n = 0; n < 2; ++n) acc[m][n] = zf;

  auto stage = [&](int bb, int k0) {
    #pragma unroll
    for (int i = 0; i < 2; ++i) {            // A: 64x64 = 8KB = 2 issues
      int base = i * 4096 + wave * 1024;
      int L = base + lane * 16;
      int row = L >> 7, lsl = ((L >> 4) & 7) ^ (row & 7);
      gld16((const char*)A + ((size_t)(brow + row) * K + k0) * 2 + lsl * 16,
            (char*)&As[bb][0] + base);
    }
    #pragma unroll
    for (int i = 0; i < 2; ++i) {            // B: 64x64 = 8KB = 2 issues
      int base = i * 4096 + wave * 1024;
      int L = base + lane * 16;
      int row = L >> 7, lsl = ((L >> 4) & 7) ^ (row & 7);
      gld16((const char*)Bw + ((size_t)(bcol + row) * K + k0) * 2 + lsl * 16,
            (char*)&Bs[bb][0] + base);
    }
  };

  stage(0, 0);
  int cur = 0;
  for (int k0 = 0; k0 < K; k0 += 64) {
    __syncthreads();                          // drains prev stage (vmcnt)
    if (k0 + 64 < K) stage(cur ^ 1, k0 + 64);
    const char* Ac = (const char*)&As[cur][0];
    const char* Bc = (const char*)&Bs[cur][0];
    short8 af[2][2], bfr[2][2];
    #pragma unroll
    for (int m = 0; m < 2; ++m) {
      int row = wr * 32 + m * 16 + r;
      #pragma unroll
      for (int kk = 0; kk < 2; ++kk)
        af[m][kk] = *reinterpret_cast<const short8*>(
            Ac + row * 128 + ((kk * 64 + g * 16) ^ ((row & 7) << 4)));
    }
    #pragma unroll
    for (int n = 0; n < 2; ++n) {
      int row = wc * 32 + n * 16 + r;
      #pragma unroll
      for (int kk = 0; kk < 2; ++kk)
        bfr[n][kk] = *reinterpret_cast<const short8*>(
            Bc + row * 128 + ((kk * 64 + g * 16) ^ ((row & 7) << 4)));
    }
    #pragma unroll
    for (int kk = 0; kk < 2; ++kk)
      #pragma unroll
      for (int m = 0; m < 2; ++m)
        #pragma unroll
        for (int n = 0; n < 2; ++n)
          acc[m][n] = __builtin_amdgcn_mfma_f32_16x16x32_bf16(af[m][kk], bfr[n][kk], acc[m][n], 0, 0, 0);
    cur ^= 1;
  }

  #pragma unroll
  for (int n = 0; n < 2; ++n) {
    int col = bcol + wc * 32 + n * 16 + r;
    float bv = bias[col];
    #pragma unroll
    for (int m = 0; m < 2; ++m) {
      #pragma unroll
      for (int reg = 0; reg < 4; ++reg) {
        int row = brow + wr * 32 + m * 16 + g * 4 + reg;
        float v = acc[m][n][reg] + bv;
        if (OUT_BF16)
          ((unsigned short*)Cout)[(size_t)row * N + col] = f2bf(v * oscale);
        else
          ((float*)Cout)[(size_t)row * N + col] = v;
      }
    }
  }
}

// Flash attention (R18-verified, verbatim — best measured 42.4us).
// Block = 8 waves = 4 q-subtiles(32 rows) x 2 kv-streams (exact split: no-max
// softmax is an order-free kv sum), double-buffered per stream. qhb =
// bf16(q*sqrt(c)): S = qhb.qhb = q.q*c exactly; V carries sqrt(c), un-scaled
// in epilogue. Grid 512 (16 qtiles x 32 slabs), XCD swizzle; LDS 64KB ->
// 2 blocks/CU = 16 waves/CU.
__global__ __launch_bounds__(512) void attn_kernel(
    const unsigned short* __restrict__ qhb,
    const unsigned short* __restrict__ vtb,
    unsigned short* __restrict__ ob) {
  const int bid = blockIdx.x;            // 0..511
  const int xcd = bid & 7, idx = bid >> 3;   // idx 0..63
  const int slab = xcd * 4 + (idx >> 4);
  const int qtile = idx & 15;            // 128 q-rows per block
  const unsigned short* Qs = qhb + (size_t)slab * NS * HD;   // K and Q source
  const unsigned short* Vts = vtb + (size_t)slab * HD * NS;  // [64][2048] pi-perm
  unsigned short* Os = ob + (size_t)slab * NS * HD;
  const int tid = threadIdx.x;
  const int lane = tid & 63;
  const int wave = tid >> 6;             // 0..7
  const int qsub = wave >> 1;            // 0..3: which 32 q-rows
  const int h = wave & 1;                // 0/1: kv stream
  const int g = lane >> 4, r = lane & 15;
  const int qrow0 = qtile * 128 + qsub * 32;
  const int rkey = (r & 7) << 4;

  __shared__ __align__(16) unsigned short K_lds[2][2][KVBLK * HD];   // [h][buf]
  __shared__ __align__(16) unsigned short Vt_lds[2][2][HD * KVBLK];  // [h][buf]

  // stream h's tile t = global kv tile 2t+h; staged by the 4 waves of
  // stream h (2 gld16 per tensor per wave).
  auto stage = [&](int bb, int t) {
    int kt2 = 2 * t + h;
    const char* Kg = (const char*)Qs + (size_t)kt2 * 8192;   // 8KB K tile
    const char* Vg = (const char*)Vts + (size_t)kt2 * 128;   // col offset
    #pragma unroll
    for (int i = 0; i < 2; ++i) {
      int base = (qsub * 2 + i) * 1024;
      int L = base + lane * 16;
      int row = L >> 7, lsl = ((L >> 4) & 7) ^ (row & 7);
      gld16(Kg + row * 128 + lsl * 16, (char*)&K_lds[h][bb][0] + base);
      gld16(Vg + (size_t)row * (NS * 2) + lsl * 16, (char*)&Vt_lds[h][bb][0] + base);
    }
  };

  // Q fragments (half-scaled): B operand of swapped QK^T:
  // col q = qrow0 + m*16 + r, k d = kk*32 + g*8..+7
  short8 aq[2][2];
  #pragma unroll
  for (int m = 0; m < 2; ++m)
    #pragma unroll
    for (int kk = 0; kk < 2; ++kk)
      aq[m][kk] = *reinterpret_cast<const short8*>(
          &Qs[(size_t)(qrow0 + m * 16 + r) * HD + kk * 32 + g * 8]);

  const f32x4 zf = {0.f, 0.f, 0.f, 0.f};
  f32x4 o_acc[2][4];
  float l_lane[2] = {0.f, 0.f};          // partial l for q = m*16 + r
  #pragma unroll
  for (int m = 0; m < 2; ++m)
    #pragma unroll
    for (int n = 0; n < 4; ++n) o_acc[m][n] = zf;

  stage(0, 0);
  int cur = 0;
  for (int t = 0; t < NS / KVBLK / 2; ++t) {   // 16 iters per stream
    __syncthreads();                          // staged tiles visible
    if (t + 1 < NS / KVBLK / 2) stage(cur ^ 1, t + 1);
    const char* Kc = (const char*)&K_lds[h][cur][0];
    const char* Vc = (const char*)&Vt_lds[h][cur][0];

    // S^T = K Q^T : lane(g,r) gets S[kv=jb*16+g*4+reg][q=m*16+r]
    f32x4 s[2][4];
    __builtin_amdgcn_s_setprio(1);
    #pragma unroll
    for (int jb = 0; jb < 4; ++jb) {
      short8 bk[2];
      #pragma unroll
      for (int kk = 0; kk < 2; ++kk)
        bk[kk] = *reinterpret_cast<const short8*>(
            Kc + (jb * 16 + r) * 128 + ((kk * 64 + g * 16) ^ rkey));
      #pragma unroll
      for (int m = 0; m < 2; ++m) {
        s[m][jb] = zf;
        #pragma unroll
        for (int kk = 0; kk < 2; ++kk)
          s[m][jb] = __builtin_amdgcn_mfma_f32_16x16x32_bf16(bk[kk], aq[m][kk], s[m][jb], 0, 0, 0);
      }
    }
    __builtin_amdgcn_s_setprio(0);

    // p = 2^(s); row-sum into per-lane l; pack PV A-frags in-register:
    // ap[m][kk][j] = P[q=m*16+r][kv = kk*32 + (j>>2)*16 + g*4 + (j&3)]
    short8 ap[2][2];
    #pragma unroll
    for (int m = 0; m < 2; ++m) {
      float p[4][4];
      #pragma unroll
      for (int jb = 0; jb < 4; ++jb)
        #pragma unroll
        for (int reg = 0; reg < 4; ++reg)
          p[jb][reg] = __builtin_amdgcn_exp2f(s[m][jb][reg]);
      float t0 = (p[0][0] + p[0][1]) + (p[0][2] + p[0][3]);
      float t1 = (p[1][0] + p[1][1]) + (p[1][2] + p[1][3]);
      float t2 = (p[2][0] + p[2][1]) + (p[2][2] + p[2][3]);
      float t3 = (p[3][0] + p[3][1]) + (p[3][2] + p[3][3]);
      l_lane[m] += (t0 + t1) + (t2 + t3);
      #pragma unroll
      for (int kk = 0; kk < 2; ++kk) {
        u32x4 w;
        w.x = cvt_pk_bf16(p[2 * kk][0], p[2 * kk][1]);
        w.y = cvt_pk_bf16(p[2 * kk][2], p[2 * kk][3]);
        w.z = cvt_pk_bf16(p[2 * kk + 1][0], p[2 * kk + 1][1]);
        w.w = cvt_pk_bf16(p[2 * kk + 1][2], p[2 * kk + 1][3]);
        ap[m][kk] = __builtin_bit_cast(short8, w);
      }
    }

    // O += P V (pi order): B[k_pv][col=d] from Vt_lds rows n*16+r
    __builtin_amdgcn_s_setprio(1);
    #pragma unroll
    for (int n = 0; n < 4; ++n) {
      short8 bv[2];
      #pragma unroll
      for (int kk = 0; kk < 2; ++kk)
        bv[kk] = *reinterpret_cast<const short8*>(
            Vc + (n * 16 + r) * 128 + ((kk * 64 + g * 16) ^ rkey));
      #pragma unroll
      for (int m = 0; m < 2; ++m)
        #pragma unroll
        for (int kk = 0; kk < 2; ++kk)
          o_acc[m][n] = __builtin_amdgcn_mfma_f32_16x16x32_bf16(ap[m][kk], bv[kk], o_acc[m][n], 0, 0, 0);
    }
    __builtin_amdgcn_s_setprio(0);
    cur ^= 1;
  }

  // cross-stream reduction through the (now dead) staging LDS.
  __syncthreads();                       // all staging/compute complete
  char* redO = (char*)&K_lds[0][0][0];
  char* redL = (char*)&Vt_lds[0][0][0];
  if (h == 1) {
    #pragma unroll
    for (int m = 0; m < 2; ++m)
      #pragma unroll
      for (int n = 0; n < 4; ++n)
        *reinterpret_cast<f32x4*>(redO + qsub * 8192 + (m * 4 + n) * 1024 + lane * 16) = o_acc[m][n];
    float2 lp; lp.x = l_lane[0]; lp.y = l_lane[1];
    *reinterpret_cast<float2*>(redL + qsub * 512 + lane * 8) = lp;
  }
  __syncthreads();
  if (h == 0) {
    #pragma unroll
    for (int m = 0; m < 2; ++m)
      #pragma unroll
      for (int n = 0; n < 4; ++n)
        o_acc[m][n] += *reinterpret_cast<f32x4*>(
            redO + qsub * 8192 + (m * 4 + n) * 1024 + lane * 16);
    float2 lp = *reinterpret_cast<float2*>(redL + qsub * 512 + lane * 8);
    l_lane[0] += lp.x; l_lane[1] += lp.y;

    // epilogue: complete l across g-lanes, normalize, un-scale V's sqrt(c)
    const float rsqc = 1.0f / sqrtf(SEXP2);   // compile-time folded
    #pragma unroll
    for (int m = 0; m < 2; ++m) {
      float l = l_lane[m];
      l += __shfl_xor(l, 16);
      l += __shfl_xor(l, 32);                 // all lanes: full l[q=m*16+r]
      #pragma unroll
      for (int reg = 0; reg < 4; ++reg) {
        float inv = rsqc / __shfl(l, g * 4 + reg);
        int row = qrow0 + m * 16 + g * 4 + reg;
        #pragma unroll
        for (int n = 0; n < 4; ++n)
          Os[(size_t)row * HD + n * 16 + r] = f2bf(o_acc[m][n][reg] * inv);
      }
    }
  }
}

extern "C" void kernel_launch(void* const* d_in, const int* in_sizes, int n_in,
                              void* d_out, int out_size, void* d_ws, size_t ws_size,
                              hipStream_t stream) {
  const float* x  = (const float*)d_in[0];
  const float* wq = (const float*)d_in[1];
  const float* bq = (const float*)d_in[2];
  const float* wu = (const float*)d_in[3];
  const float* bu = (const float*)d_in[4];
  float* out = (float*)d_out;

  char* ws = (char*)d_ws;
  unsigned short* xb  = (unsigned short*)(ws);                 // 8 MB (reused as vtb)
  unsigned short* qhb = (unsigned short*)(ws + (8u  << 20));   // 8 MB: bf16(q*sqrt(c))
  unsigned short* ob  = (unsigned short*)(ws + (16u << 20));   // 8 MB: attn output
  unsigned short* wqb = (unsigned short*)(ws + (24u << 20));   // 2 MB
  unsigned short* wub = (unsigned short*)(ws + (26u << 20));   // 2 MB

  // all three f32->bf16 conversions in one launch
  const int nx = NTOK * EMB, nw = EMB * EMB;
  cvt_bf16x3_kernel<<<((nx + 2 * nw) / 8 + 255) / 256, 256, 0, stream>>>(
      x, xb, nx, wq, wqb, nw, wu, wub, nw);

  // q = x @ wq^T + bq -> qhb = bf16(q * sqrt(c)), single rounded
  gemm_bt_kernel<true><<<dim3(1024), 256, 0, stream>>>(
      xb, wqb, bq, qhb, sqrtf(SEXP2), NTOK, EMB, EMB);

  // xb is dead now; reuse as vtb: per-slab pi-permuted transpose of qhb
  unsigned short* vtb = xb;
  transpose_kernel<<<dim3(NS / 64, HEADS * NB), 256, 0, stream>>>(qhb, vtb);

  // 512 blocks (16 qtiles x 32 slabs) x 512 threads; XCD swizzle in-kernel
  attn_kernel<<<dim3(512), 512, 0, stream>>>(qhb, vtb, ob);

  // y = O @ wu^T + bu -> f32
  gemm_bt_kernel<false><<<dim3(1024), 256, 0, stream>>>(
      ob, wub, bu, out, 1.0f, NTOK, EMB, EMB);
}